// Round 7
// baseline (134.977 us; speedup 1.0000x reference)
//
#include <hip/hip_runtime.h>
#include <hip/hip_bf16.h>

typedef __attribute__((ext_vector_type(8))) short short8;
typedef __attribute__((ext_vector_type(4))) float f32x4;

__device__ __forceinline__ unsigned short f2b(float x) {
  union { float f; unsigned u; } v; v.f = x;
  unsigned r = v.u + 0x7fffu + ((v.u >> 16) & 1u);
  return (unsigned short)(r >> 16);
}

// pack 4 f32 -> 4 bf16 (RNE) via 2x v_cvt_pk_bf16_f32
__device__ __forceinline__ ushort4 pack4(float4 f) {
  union { __hip_bfloat162 h[2]; ushort4 s; } u;
  u.h[0] = __float22bfloat162_rn(float2{f.x, f.y});
  u.h[1] = __float22bfloat162_rn(float2{f.z, f.w});
  return u.s;
}

// ---- prep: transpose + bf16-convert weights into workspace ----
// W1T [512][128]: rows 0..255 = Wv^T; rows 256..511 = Wg^T with columns
// pre-permuted so gate channel for output c=h*64+d sits at row 256+c
// (gate source col g = d*4+h => dest row 256 + (g&3)*64 + (g>>2)).
// WoT [128][256] = Wo^T.  bg2[256] = permuted gate bias.
__global__ __launch_bounds__(256) void prep_kernel(
    const float* __restrict__ Wv, const float* __restrict__ Wg,
    const float* __restrict__ bgv, const float* __restrict__ Wo,
    unsigned short* __restrict__ W1T, unsigned short* __restrict__ WoT,
    float* __restrict__ bg2)
{
  int t = blockIdx.x * 256 + threadIdx.x;
  if (t < 32768) {                      // Wv: src [e][c]
    int e = t >> 8, c = t & 255;
    W1T[c * 128 + e] = f2b(Wv[t]);
  } else if (t < 65536) {               // Wg: src [e][g]
    int s = t - 32768;
    int e = s >> 8, g = s & 255;
    int cc = ((g & 3) << 6) + (g >> 2); // cc = h*64+d
    W1T[(256 + cc) * 128 + e] = f2b(Wg[s]);
  } else if (t < 65536 + 32768) {       // Wo: src [c][o]
    int s = t - 65536;
    int c = s >> 7, o = s & 127;
    WoT[o * 256 + c] = f2b(Wo[s]);
  } else if (t < 65536 + 32768 + 256) {
    int g = t - (65536 + 32768);
    bg2[((g & 3) << 6) + (g >> 2)] = bgv[g];
  }
}

// ---- fused, persistent-weight, deep-pipelined ----
// 8 waves, weights in VGPRs (96 regs/lane, zero duplication), 8x32-row tiles,
// FULLY UNROLLED loop (static LDS addressing), ~2.5-iteration-deep X
// prefetch: prologue issues tiles 1,2; iter i waits tile i+1 (issued a full
// iteration earlier -> latency hidden) and re-issues tile i+3.
__global__ __launch_bounds__(512, 2) void fused_kernel(
    const float* __restrict__ X,              // [65536][128] f32
    const unsigned short* __restrict__ W1T,   // [512][128] bf16
    const unsigned short* __restrict__ WoT,   // [128][256] bf16
    const float* __restrict__ bg2,            // [256]
    const float* __restrict__ bo,             // [128]
    float* __restrict__ Out)                  // [65536][128] f32
{
  __shared__ unsigned short Xs[2][32 * 128];  // 2 x 8KB, XOR-swizzled
  __shared__ unsigned short Ys[2][32 * 256];  // 2 x 16KB, XOR-swizzled

  const int tid  = threadIdx.x;
  const int lane = tid & 63;
  const int wave = tid >> 6;                  // 0..7
  const int l15  = lane & 15;
  const int lhi  = lane >> 4;
  const long rowbase0 = (long)blockIdx.x * 256;

  // ---- persistent weights (once per block): 96 VGPR/lane total ----
  short8 wS1[2][4][2];                        // [c-tile t][ks][V=0,G=1]
  float  bgt[2];
  #pragma unroll
  for (int t = 0; t < 2; ++t) {
    int c0 = (wave * 2 + t) * 16;
    const unsigned short* base = W1T + (c0 + l15) * 128 + lhi * 8;
    #pragma unroll
    for (int ks = 0; ks < 4; ++ks) {
      wS1[t][ks][0] = *reinterpret_cast<const short8*>(base + ks * 32);
      wS1[t][ks][1] = *reinterpret_cast<const short8*>(base + ks * 32 + 256 * 128);
    }
    bgt[t] = bg2[c0 + l15];
  }
  short8 wS2[8];
  const int o0 = wave * 16;                   // this wave's 16 output cols
  #pragma unroll
  for (int ks = 0; ks < 8; ++ks)
    wS2[ks] = *reinterpret_cast<const short8*>(WoT + (o0 + l15) * 256 + ks * 32 + lhi * 8);
  const float bov = bo[o0 + l15];

  // per-thread staging geometry (thread covers float4 #tid and #512+tid)
  const int r0 = tid >> 5,        c0v = (tid & 31) * 4;
  const int s0w = (r0 * 128 + c0v) ^ ((r0 & 7) << 3);
  const int r1 = (512 + tid) >> 5, c1v = (tid & 31) * 4;
  const int s1w = (r1 * 128 + c1v) ^ ((r1 & 7) << 3);

  // ---- prologue: stage tile 0; issue tiles 1 (set1) and 2 (set0) ----
  {
    const float4* Xp = reinterpret_cast<const float4*>(X + rowbase0 * 128);
    float4 a = Xp[tid], b = Xp[512 + tid];
    *reinterpret_cast<ushort4*>(&Xs[0][s0w]) = pack4(a);
    *reinterpret_cast<ushort4*>(&Xs[0][s1w]) = pack4(b);
  }
  float4 pf[2][2];
  {
    const float4* Xp = reinterpret_cast<const float4*>(X + (rowbase0 + 32) * 128);
    pf[1][0] = Xp[tid]; pf[1][1] = Xp[512 + tid];          // tile 1 -> set1
  }
  {
    const float4* Xp = reinterpret_cast<const float4*>(X + (rowbase0 + 64) * 128);
    pf[0][0] = Xp[tid]; pf[0][1] = Xp[512 + tid];          // tile 2 -> set0
  }
  __syncthreads();

  const f32x4 vzero = {0.f, 0.f, 0.f, 0.f};

  #pragma unroll
  for (int i = 0; i < 8; ++i) {
    const int cb = i & 1;                     // compile-time under full unroll

    // ---- A: X fragments from Xs[cb] (static base) ----
    short8 afrag[2][4];
    #pragma unroll
    for (int mt = 0; mt < 2; ++mt) {
      int row = mt * 16 + l15;
      #pragma unroll
      for (int ks = 0; ks < 4; ++ks) {
        int sidx = (row * 128 + ks * 32 + lhi * 8) ^ ((row & 7) << 3);
        afrag[mt][ks] = *reinterpret_cast<const short8*>(&Xs[cb][sidx]);
      }
    }

    // ---- stage 1: V/G MFMA (in-reg weights), gate, write Ys[cb] ----
    __builtin_amdgcn_s_setprio(1);
    f32x4 accV[2][2], accG[2][2];
    #pragma unroll
    for (int t = 0; t < 2; ++t) {
      #pragma unroll
      for (int mt = 0; mt < 2; ++mt) { accV[t][mt] = vzero; accG[t][mt] = vzero; }
      #pragma unroll
      for (int ks = 0; ks < 4; ++ks) {
        #pragma unroll
        for (int mt = 0; mt < 2; ++mt) {
          accV[t][mt] = __builtin_amdgcn_mfma_f32_16x16x32_bf16(afrag[mt][ks], wS1[t][ks][0], accV[t][mt], 0, 0, 0);
          accG[t][mt] = __builtin_amdgcn_mfma_f32_16x16x32_bf16(afrag[mt][ks], wS1[t][ks][1], accG[t][mt], 0, 0, 0);
        }
      }
    }
    __builtin_amdgcn_s_setprio(0);
    #pragma unroll
    for (int t = 0; t < 2; ++t) {
      int c0 = (wave * 2 + t) * 16;
      #pragma unroll
      for (int mt = 0; mt < 2; ++mt) {
        #pragma unroll
        for (int r = 0; r < 4; ++r) {
          int row = mt * 16 + lhi * 4 + r;    // C/D: col=lane&15, row=(lane>>4)*4+r
          float z = accG[t][mt][r] + bgt[t];
          float g = 1.0f / (1.0f + __expf(-z));
          float y = g * accV[t][mt][r];
          int sidx = (row * 256 + c0 + l15) ^ ((row & 7) << 3);
          Ys[cb][sidx] = f2b(y);
        }
      }
    }

    // ---- drain tile i+1 -> Xs[cb^1]; re-issue tile i+3 into freed set ----
    if (i < 7) {
      const int ps = (i + 1) & 1;             // static
      float4 a = pf[ps][0], b = pf[ps][1];    // waits vmcnt here (issued >=1 iter ago)
      *reinterpret_cast<ushort4*>(&Xs[ps][s0w]) = pack4(a);
      *reinterpret_cast<ushort4*>(&Xs[ps][s1w]) = pack4(b);
      if (i < 5) {
        const float4* Xp = reinterpret_cast<const float4*>(X + (rowbase0 + (long)(i + 3) * 32) * 128);
        pf[ps][0] = Xp[tid]; pf[ps][1] = Xp[512 + tid];
      }
    }

    __syncthreads();   // Ys[cb] + Xs[cb^1] ready; Xs[cb] now dead

    // ---- stage 2: Out tile = Ys[cb] @ Wo + bo (in-reg weights) ----
    f32x4 acc2[2] = {vzero, vzero};
    #pragma unroll
    for (int ks = 0; ks < 8; ++ks) {
      #pragma unroll
      for (int mt = 0; mt < 2; ++mt) {
        int row = mt * 16 + l15;
        int sidx = (row * 256 + ks * 32 + lhi * 8) ^ ((row & 7) << 3);
        short8 a = *reinterpret_cast<const short8*>(&Ys[cb][sidx]);
        acc2[mt] = __builtin_amdgcn_mfma_f32_16x16x32_bf16(a, wS2[ks], acc2[mt], 0, 0, 0);
      }
    }
    const long rowb = rowbase0 + (long)i * 32;
    #pragma unroll
    for (int mt = 0; mt < 2; ++mt) {
      #pragma unroll
      for (int r = 0; r < 4; ++r) {
        Out[(rowb + mt * 16 + lhi * 4 + r) * 128 + o0 + l15] = acc2[mt][r] + bov;
      }
    }
    // no second barrier: iter i+1 writes Ys[cb^1] and reads Xs[cb^1], both
    // sequenced correctly around this iteration's barrier.
  }
}

extern "C" void kernel_launch(void* const* d_in, const int* in_sizes, int n_in,
                              void* d_out, int out_size, void* d_ws, size_t ws_size,
                              hipStream_t stream) {
  // inputs: 0 inter_edges, 1 ab_mask, 2 at_mask, 3 Wq, 4 Wk, 5 Wv, 6 Web,
  //         7 Wg, 8 bg, 9 Wo, 10 bo   (Wq/Wk/Web/masks mathematically unused)
  const float* X   = (const float*)d_in[0];
  const float* Wv  = (const float*)d_in[5];
  const float* Wg  = (const float*)d_in[7];
  const float* bg  = (const float*)d_in[8];
  const float* Wo  = (const float*)d_in[9];
  const float* bo  = (const float*)d_in[10];

  unsigned short* W1T = (unsigned short*)d_ws;            // 512*128 bf16
  unsigned short* WoT = W1T + 512 * 128;                  // 128*256 bf16
  float*          bg2 = (float*)(WoT + 128 * 256);        // 256 f32

  prep_kernel<<<386, 256, 0, stream>>>(Wv, Wg, bg, Wo, W1T, WoT, bg2);

  float* Out = (float*)d_out;
  fused_kernel<<<256, 512, 0, stream>>>(X, W1T, WoT, bg2, bo, Out);
}

// Round 8
// 117.320 us; speedup vs baseline: 1.1505x; 1.1505x over previous
//
#include <hip/hip_runtime.h>
#include <hip/hip_bf16.h>

typedef __attribute__((ext_vector_type(8))) short short8;
typedef __attribute__((ext_vector_type(4))) float f32x4;

__device__ __forceinline__ unsigned short f2b(float x) {
  union { float f; unsigned u; } v; v.f = x;
  unsigned r = v.u + 0x7fffu + ((v.u >> 16) & 1u);
  return (unsigned short)(r >> 16);
}

// pack 4 f32 -> 4 bf16 (RNE) via 2x v_cvt_pk_bf16_f32
__device__ __forceinline__ ushort4 pack4(float4 f) {
  union { __hip_bfloat162 h[2]; ushort4 s; } u;
  u.h[0] = __float22bfloat162_rn(float2{f.x, f.y});
  u.h[1] = __float22bfloat162_rn(float2{f.z, f.w});
  return u.s;
}

// ---- prep: transpose + bf16-convert weights into workspace ----
// W1T [512][128]: rows 0..255 = Wv^T; rows 256..511 = Wg^T with columns
// pre-permuted so gate channel for output c=h*64+d sits at row 256+c
// (gate source col g = d*4+h => dest row 256 + (g&3)*64 + (g>>2)).
// WoT [128][256] = Wo^T.  bg2[256] = permuted gate bias.
__global__ __launch_bounds__(256) void prep_kernel(
    const float* __restrict__ Wv, const float* __restrict__ Wg,
    const float* __restrict__ bgv, const float* __restrict__ Wo,
    unsigned short* __restrict__ W1T, unsigned short* __restrict__ WoT,
    float* __restrict__ bg2)
{
  int t = blockIdx.x * 256 + threadIdx.x;
  if (t < 32768) {                      // Wv: src [e][c]
    int e = t >> 8, c = t & 255;
    W1T[c * 128 + e] = f2b(Wv[t]);
  } else if (t < 65536) {               // Wg: src [e][g]
    int s = t - 32768;
    int e = s >> 8, g = s & 255;
    int cc = ((g & 3) << 6) + (g >> 2); // cc = h*64+d
    W1T[(256 + cc) * 128 + e] = f2b(Wg[s]);
  } else if (t < 65536 + 32768) {       // Wo: src [c][o]
    int s = t - 65536;
    int c = s >> 7, o = s & 127;
    WoT[o * 256 + c] = f2b(Wo[s]);
  } else if (t < 65536 + 32768 + 256) {
    int g = t - (65536 + 32768);
    bg2[((g & 3) << 6) + (g >> 2)] = bgv[g];
  }
}

// ---- fused, persistent-weight, pipelined ----
// 8 waves, weights in VGPRs (96 regs/lane), 8x32-row tiles, fully unrolled
// (static LDS addressing). Single-set 2-tile-deep X prefetch: prologue
// issues tile 1; iter i drains pf->Xs after stage-1 and re-issues tile i+2
// (consumed a full iteration later). NO min-waves launch bound: R7 showed
// __launch_bounds__(512,2) imposes a 128-VGPR cap -> 40MB of spill traffic.
// Plain (512) gives the 256-VGPR cap (8 waves must fit a CU).
__global__ __launch_bounds__(512) void fused_kernel(
    const float* __restrict__ X,              // [65536][128] f32
    const unsigned short* __restrict__ W1T,   // [512][128] bf16
    const unsigned short* __restrict__ WoT,   // [128][256] bf16
    const float* __restrict__ bg2,            // [256]
    const float* __restrict__ bo,             // [128]
    float* __restrict__ Out)                  // [65536][128] f32
{
  __shared__ unsigned short Xs[2][32 * 128];  // 2 x 8KB, XOR-swizzled
  __shared__ unsigned short Ys[2][32 * 256];  // 2 x 16KB, XOR-swizzled

  const int tid  = threadIdx.x;
  const int lane = tid & 63;
  const int wave = tid >> 6;                  // 0..7
  const int l15  = lane & 15;
  const int lhi  = lane >> 4;
  const long rowbase0 = (long)blockIdx.x * 256;

  // ---- persistent weights (once per block): 96 VGPR/lane total ----
  short8 wS1[2][4][2];                        // [c-tile t][ks][V=0,G=1]
  float  bgt[2];
  #pragma unroll
  for (int t = 0; t < 2; ++t) {
    int c0 = (wave * 2 + t) * 16;
    const unsigned short* base = W1T + (c0 + l15) * 128 + lhi * 8;
    #pragma unroll
    for (int ks = 0; ks < 4; ++ks) {
      wS1[t][ks][0] = *reinterpret_cast<const short8*>(base + ks * 32);
      wS1[t][ks][1] = *reinterpret_cast<const short8*>(base + ks * 32 + 256 * 128);
    }
    bgt[t] = bg2[c0 + l15];
  }
  short8 wS2[8];
  const int o0 = wave * 16;                   // this wave's 16 output cols
  #pragma unroll
  for (int ks = 0; ks < 8; ++ks)
    wS2[ks] = *reinterpret_cast<const short8*>(WoT + (o0 + l15) * 256 + ks * 32 + lhi * 8);
  const float bov = bo[o0 + l15];

  // per-thread staging geometry (thread covers float4 #tid and #512+tid)
  const int r0 = tid >> 5,        c0v = (tid & 31) * 4;
  const int s0w = (r0 * 128 + c0v) ^ ((r0 & 7) << 3);
  const int r1 = (512 + tid) >> 5;
  const int s1w = (r1 * 128 + c0v) ^ ((r1 & 7) << 3);

  // ---- prologue: stage tile 0; issue tile 1 into pf ----
  {
    const float4* Xp = reinterpret_cast<const float4*>(X + rowbase0 * 128);
    float4 a = Xp[tid], b = Xp[512 + tid];
    *reinterpret_cast<ushort4*>(&Xs[0][s0w]) = pack4(a);
    *reinterpret_cast<ushort4*>(&Xs[0][s1w]) = pack4(b);
  }
  float4 pf0, pf1;
  {
    const float4* Xp = reinterpret_cast<const float4*>(X + (rowbase0 + 32) * 128);
    pf0 = Xp[tid]; pf1 = Xp[512 + tid];
  }
  __syncthreads();

  const f32x4 vzero = {0.f, 0.f, 0.f, 0.f};

  #pragma unroll
  for (int i = 0; i < 8; ++i) {
    const int cb = i & 1;                     // compile-time under full unroll

    // ---- A: X fragments from Xs[cb] (static base) ----
    short8 afrag[2][4];
    #pragma unroll
    for (int mt = 0; mt < 2; ++mt) {
      int row = mt * 16 + l15;
      #pragma unroll
      for (int ks = 0; ks < 4; ++ks) {
        int sidx = (row * 128 + ks * 32 + lhi * 8) ^ ((row & 7) << 3);
        afrag[mt][ks] = *reinterpret_cast<const short8*>(&Xs[cb][sidx]);
      }
    }

    // ---- stage 1: V/G MFMA (in-reg weights), gate, write Ys[cb] ----
    __builtin_amdgcn_s_setprio(1);
    f32x4 accV[2][2], accG[2][2];
    #pragma unroll
    for (int t = 0; t < 2; ++t) {
      #pragma unroll
      for (int mt = 0; mt < 2; ++mt) { accV[t][mt] = vzero; accG[t][mt] = vzero; }
      #pragma unroll
      for (int ks = 0; ks < 4; ++ks) {
        #pragma unroll
        for (int mt = 0; mt < 2; ++mt) {
          accV[t][mt] = __builtin_amdgcn_mfma_f32_16x16x32_bf16(afrag[mt][ks], wS1[t][ks][0], accV[t][mt], 0, 0, 0);
          accG[t][mt] = __builtin_amdgcn_mfma_f32_16x16x32_bf16(afrag[mt][ks], wS1[t][ks][1], accG[t][mt], 0, 0, 0);
        }
      }
    }
    __builtin_amdgcn_s_setprio(0);
    #pragma unroll
    for (int t = 0; t < 2; ++t) {
      int c0 = (wave * 2 + t) * 16;
      #pragma unroll
      for (int mt = 0; mt < 2; ++mt) {
        #pragma unroll
        for (int r = 0; r < 4; ++r) {
          int row = mt * 16 + lhi * 4 + r;    // C/D: col=lane&15, row=(lane>>4)*4+r
          float z = accG[t][mt][r] + bgt[t];
          float g = 1.0f / (1.0f + __expf(-z));
          float y = g * accV[t][mt][r];
          int sidx = (row * 256 + c0 + l15) ^ ((row & 7) << 3);
          Ys[cb][sidx] = f2b(y);
        }
      }
    }

    // ---- drain tile i+1 -> Xs[cb^1]; re-issue tile i+2 into pf ----
    if (i < 7) {
      float4 a = pf0, b = pf1;   // vmcnt wait here: issued a full iter ago
      *reinterpret_cast<ushort4*>(&Xs[cb ^ 1][s0w]) = pack4(a);
      *reinterpret_cast<ushort4*>(&Xs[cb ^ 1][s1w]) = pack4(b);
      if (i < 6) {
        const float4* Xp = reinterpret_cast<const float4*>(X + (rowbase0 + (long)(i + 2) * 32) * 128);
        pf0 = Xp[tid]; pf1 = Xp[512 + tid];
      }
    }

    __syncthreads();   // Ys[cb] + Xs[cb^1] ready; Xs[cb] now dead

    // ---- stage 2: Out tile = Ys[cb] @ Wo + bo (in-reg weights) ----
    f32x4 acc2[2] = {vzero, vzero};
    #pragma unroll
    for (int ks = 0; ks < 8; ++ks) {
      #pragma unroll
      for (int mt = 0; mt < 2; ++mt) {
        int row = mt * 16 + l15;
        int sidx = (row * 256 + ks * 32 + lhi * 8) ^ ((row & 7) << 3);
        short8 a = *reinterpret_cast<const short8*>(&Ys[cb][sidx]);
        acc2[mt] = __builtin_amdgcn_mfma_f32_16x16x32_bf16(a, wS2[ks], acc2[mt], 0, 0, 0);
      }
    }
    const long rowb = rowbase0 + (long)i * 32;
    #pragma unroll
    for (int mt = 0; mt < 2; ++mt) {
      #pragma unroll
      for (int r = 0; r < 4; ++r) {
        Out[(rowb + mt * 16 + lhi * 4 + r) * 128 + o0 + l15] = acc2[mt][r] + bov;
      }
    }
    // no second barrier: iter i+1 writes Ys[cb^1] and reads Xs[cb^1], both
    // sequenced correctly around this iteration's barrier.
  }
}

extern "C" void kernel_launch(void* const* d_in, const int* in_sizes, int n_in,
                              void* d_out, int out_size, void* d_ws, size_t ws_size,
                              hipStream_t stream) {
  // inputs: 0 inter_edges, 1 ab_mask, 2 at_mask, 3 Wq, 4 Wk, 5 Wv, 6 Web,
  //         7 Wg, 8 bg, 9 Wo, 10 bo   (Wq/Wk/Web/masks mathematically unused)
  const float* X   = (const float*)d_in[0];
  const float* Wv  = (const float*)d_in[5];
  const float* Wg  = (const float*)d_in[7];
  const float* bg  = (const float*)d_in[8];
  const float* Wo  = (const float*)d_in[9];
  const float* bo  = (const float*)d_in[10];

  unsigned short* W1T = (unsigned short*)d_ws;            // 512*128 bf16
  unsigned short* WoT = W1T + 512 * 128;                  // 128*256 bf16
  float*          bg2 = (float*)(WoT + 128 * 256);        // 256 f32

  prep_kernel<<<386, 256, 0, stream>>>(Wv, Wg, bg, Wo, W1T, WoT, bg2);

  float* Out = (float*)d_out;
  fused_kernel<<<256, 512, 0, stream>>>(X, W1T, WoT, bg2, bo, Out);
}

// Round 9
// 115.904 us; speedup vs baseline: 1.1646x; 1.0122x over previous
//
#include <hip/hip_runtime.h>
#include <hip/hip_bf16.h>

typedef __attribute__((ext_vector_type(8))) short short8;
typedef __attribute__((ext_vector_type(4))) float f32x4;

__device__ __forceinline__ unsigned short f2b(float x) {
  union { float f; unsigned u; } v; v.f = x;
  unsigned r = v.u + 0x7fffu + ((v.u >> 16) & 1u);
  return (unsigned short)(r >> 16);
}

// pack 4 f32 -> 4 bf16 (RNE) via 2x v_cvt_pk_bf16_f32
__device__ __forceinline__ ushort4 pack4(float4 f) {
  union { __hip_bfloat162 h[2]; ushort4 s; } u;
  u.h[0] = __float22bfloat162_rn(float2{f.x, f.y});
  u.h[1] = __float22bfloat162_rn(float2{f.z, f.w});
  return u.s;
}

// ---- prep: transpose + bf16-convert weights into workspace ----
// W1T [512][128]: rows 0..255 = Wv^T; rows 256..511 = Wg^T with columns
// pre-permuted so gate channel for output c=h*64+d sits at row 256+c
// (gate source col g = d*4+h => dest row 256 + (g&3)*64 + (g>>2)).
// WoT [128][256] = Wo^T.  bg2[256] = permuted gate bias.
__global__ __launch_bounds__(256) void prep_kernel(
    const float* __restrict__ Wv, const float* __restrict__ Wg,
    const float* __restrict__ bgv, const float* __restrict__ Wo,
    unsigned short* __restrict__ W1T, unsigned short* __restrict__ WoT,
    float* __restrict__ bg2)
{
  int t = blockIdx.x * 256 + threadIdx.x;
  if (t < 32768) {                      // Wv: src [e][c]
    int e = t >> 8, c = t & 255;
    W1T[c * 128 + e] = f2b(Wv[t]);
  } else if (t < 65536) {               // Wg: src [e][g]
    int s = t - 32768;
    int e = s >> 8, g = s & 255;
    int cc = ((g & 3) << 6) + (g >> 2); // cc = h*64+d
    W1T[(256 + cc) * 128 + e] = f2b(Wg[s]);
  } else if (t < 65536 + 32768) {       // Wo: src [c][o]
    int s = t - 65536;
    int c = s >> 7, o = s & 127;
    WoT[o * 256 + c] = f2b(Wo[s]);
  } else if (t < 65536 + 32768 + 256) {
    int g = t - (65536 + 32768);
    bg2[((g & 3) << 6) + (g >> 2)] = bgv[g];
  }
}

// ---- fused, persistent-weight, 2-stage modulo-pipelined ----
// 8 waves, weights in VGPRs (96/lane), 32-row tiles fully unrolled.
// Body(i) = { stage2(tile i) || stage1(tile i+1) || prefetch drain/issue },
// ONE barrier per body: the wave holds two independent instruction streams
// between barriers (stage2 reads Ys[i&1]; stage1 reads Xs[(i+1)&1], writes
// Ys[(i+1)&1]) -> compiler interleaves them to cover LDS/MFMA/VALU latency
// that 2 waves/SIMD alone cannot hide.
__global__ __launch_bounds__(512) void fused_kernel(
    const float* __restrict__ X,              // [65536][128] f32
    const unsigned short* __restrict__ W1T,   // [512][128] bf16
    const unsigned short* __restrict__ WoT,   // [128][256] bf16
    const float* __restrict__ bg2,            // [256]
    const float* __restrict__ bo,             // [128]
    float* __restrict__ Out)                  // [65536][128] f32
{
  __shared__ unsigned short Xs[2][32 * 128];  // 2 x 8KB, XOR-swizzled
  __shared__ unsigned short Ys[2][32 * 256];  // 2 x 16KB, XOR-swizzled

  const int tid  = threadIdx.x;
  const int lane = tid & 63;
  const int wave = tid >> 6;                  // 0..7
  const int l15  = lane & 15;
  const int lhi  = lane >> 4;
  const long rowbase0 = (long)blockIdx.x * 256;

  // ---- persistent weights (once per block): 96 VGPR/lane ----
  short8 wS1[2][4][2];                        // [c-tile t][ks][V=0,G=1]
  float  bgt[2];
  #pragma unroll
  for (int t = 0; t < 2; ++t) {
    int c0 = (wave * 2 + t) * 16;
    const unsigned short* base = W1T + (c0 + l15) * 128 + lhi * 8;
    #pragma unroll
    for (int ks = 0; ks < 4; ++ks) {
      wS1[t][ks][0] = *reinterpret_cast<const short8*>(base + ks * 32);
      wS1[t][ks][1] = *reinterpret_cast<const short8*>(base + ks * 32 + 256 * 128);
    }
    bgt[t] = bg2[c0 + l15];
  }
  short8 wS2[8];
  const int o0 = wave * 16;                   // this wave's 16 output cols
  #pragma unroll
  for (int ks = 0; ks < 8; ++ks)
    wS2[ks] = *reinterpret_cast<const short8*>(WoT + (o0 + l15) * 256 + ks * 32 + lhi * 8);
  const float bov = bo[o0 + l15];

  // per-thread staging geometry (thread covers float4 #tid and #512+tid)
  const int r0 = tid >> 5,        c0v = (tid & 31) * 4;
  const int s0w = (r0 * 128 + c0v) ^ ((r0 & 7) << 3);
  const int r1 = (512 + tid) >> 5;
  const int s1w = (r1 * 128 + c0v) ^ ((r1 & 7) << 3);

  float4 pf0, pf1;
  const f32x4 vzero = {0.f, 0.f, 0.f, 0.f};

  auto issuePf = [&](int k) {                 // issue X loads of tile k
    const float4* Xp = reinterpret_cast<const float4*>(X + (rowbase0 + (long)k * 32) * 128);
    pf0 = Xp[tid]; pf1 = Xp[512 + tid];
  };
  auto drainPf = [&](int k) {                 // pf (tile k) -> Xs[k&1]
    *reinterpret_cast<ushort4*>(&Xs[k & 1][s0w]) = pack4(pf0);
    *reinterpret_cast<ushort4*>(&Xs[k & 1][s1w]) = pack4(pf1);
  };

  auto stage1 = [&](int k) {                  // tile k: Xs[k&1] -> Ys[k&1]
    const int cb = k & 1;
    short8 afrag[2][4];
    #pragma unroll
    for (int mt = 0; mt < 2; ++mt) {
      int row = mt * 16 + l15;
      #pragma unroll
      for (int ks = 0; ks < 4; ++ks) {
        int sidx = (row * 128 + ks * 32 + lhi * 8) ^ ((row & 7) << 3);
        afrag[mt][ks] = *reinterpret_cast<const short8*>(&Xs[cb][sidx]);
      }
    }
    __builtin_amdgcn_s_setprio(1);
    f32x4 accV[2][2], accG[2][2];
    #pragma unroll
    for (int t = 0; t < 2; ++t) {
      #pragma unroll
      for (int mt = 0; mt < 2; ++mt) { accV[t][mt] = vzero; accG[t][mt] = vzero; }
      #pragma unroll
      for (int ks = 0; ks < 4; ++ks) {
        #pragma unroll
        for (int mt = 0; mt < 2; ++mt) {
          accV[t][mt] = __builtin_amdgcn_mfma_f32_16x16x32_bf16(afrag[mt][ks], wS1[t][ks][0], accV[t][mt], 0, 0, 0);
          accG[t][mt] = __builtin_amdgcn_mfma_f32_16x16x32_bf16(afrag[mt][ks], wS1[t][ks][1], accG[t][mt], 0, 0, 0);
        }
      }
    }
    __builtin_amdgcn_s_setprio(0);
    #pragma unroll
    for (int t = 0; t < 2; ++t) {
      int c0 = (wave * 2 + t) * 16;
      #pragma unroll
      for (int mt = 0; mt < 2; ++mt) {
        float ys[4];
        #pragma unroll
        for (int r = 0; r < 4; ++r) {
          float z = accG[t][mt][r] + bgt[t];
          float e = __expf(-z);
          ys[r] = accV[t][mt][r] * __builtin_amdgcn_rcpf(1.0f + e);
        }
        // paired bf16 convert: 2 values per v_cvt_pk_bf16_f32
        __hip_bfloat162 p01 = __float22bfloat162_rn(float2{ys[0], ys[1]});
        __hip_bfloat162 p23 = __float22bfloat162_rn(float2{ys[2], ys[3]});
        ushort2 u01 = *reinterpret_cast<ushort2*>(&p01);
        ushort2 u23 = *reinterpret_cast<ushort2*>(&p23);
        int rb = mt * 16 + lhi * 4;           // C/D: col=lane&15, row=(lane>>4)*4+r
        Ys[cb][((rb + 0) * 256 + c0 + l15) ^ (((rb + 0) & 7) << 3)] = u01.x;
        Ys[cb][((rb + 1) * 256 + c0 + l15) ^ (((rb + 1) & 7) << 3)] = u01.y;
        Ys[cb][((rb + 2) * 256 + c0 + l15) ^ (((rb + 2) & 7) << 3)] = u23.x;
        Ys[cb][((rb + 3) * 256 + c0 + l15) ^ (((rb + 3) & 7) << 3)] = u23.y;
      }
    }
  };

  auto stage2 = [&](int k) {                  // Ys[k&1] @ Wo + bo -> Out
    const int cb = k & 1;
    f32x4 acc2[2] = {vzero, vzero};
    #pragma unroll
    for (int ks = 0; ks < 8; ++ks) {
      #pragma unroll
      for (int mt = 0; mt < 2; ++mt) {
        int row = mt * 16 + l15;
        int sidx = (row * 256 + ks * 32 + lhi * 8) ^ ((row & 7) << 3);
        short8 a = *reinterpret_cast<const short8*>(&Ys[cb][sidx]);
        acc2[mt] = __builtin_amdgcn_mfma_f32_16x16x32_bf16(a, wS2[ks], acc2[mt], 0, 0, 0);
      }
    }
    const long rowb = rowbase0 + (long)k * 32;
    #pragma unroll
    for (int mt = 0; mt < 2; ++mt) {
      #pragma unroll
      for (int r = 0; r < 4; ++r) {
        Out[(rowb + mt * 16 + lhi * 4 + r) * 128 + o0 + l15] = acc2[mt][r] + bov;
      }
    }
  };

  // ---- prologue: stage tile 0 directly; issue tile 1 ----
  {
    const float4* Xp = reinterpret_cast<const float4*>(X + rowbase0 * 128);
    float4 a = Xp[tid], b = Xp[512 + tid];
    *reinterpret_cast<ushort4*>(&Xs[0][s0w]) = pack4(a);
    *reinterpret_cast<ushort4*>(&Xs[0][s1w]) = pack4(b);
    issuePf(1);
  }
  __syncthreads();

  stage1(0);            // Ys[0]
  drainPf(1);           // Xs[1]
  issuePf(2);
  __syncthreads();

  // ---- steady state: body(i) = stage2(i) || stage1(i+1) || prefetch ----
  #pragma unroll
  for (int i = 0; i < 7; ++i) {
    stage2(i);                       // reads Ys[i&1], stores rows i*32
    stage1(i + 1);                   // reads Xs[(i+1)&1], writes Ys[(i+1)&1]
    if (i + 2 <= 7) drainPf(i + 2);  // pf -> Xs[(i+2)&1] (== Xs[i&1], dead)
    if (i + 3 <= 7) issuePf(i + 3);
    __syncthreads();
  }
  stage2(7);
}

extern "C" void kernel_launch(void* const* d_in, const int* in_sizes, int n_in,
                              void* d_out, int out_size, void* d_ws, size_t ws_size,
                              hipStream_t stream) {
  // inputs: 0 inter_edges, 1 ab_mask, 2 at_mask, 3 Wq, 4 Wk, 5 Wv, 6 Web,
  //         7 Wg, 8 bg, 9 Wo, 10 bo   (Wq/Wk/Web/masks mathematically unused)
  const float* X   = (const float*)d_in[0];
  const float* Wv  = (const float*)d_in[5];
  const float* Wg  = (const float*)d_in[7];
  const float* bg  = (const float*)d_in[8];
  const float* Wo  = (const float*)d_in[9];
  const float* bo  = (const float*)d_in[10];

  unsigned short* W1T = (unsigned short*)d_ws;            // 512*128 bf16
  unsigned short* WoT = W1T + 512 * 128;                  // 128*256 bf16
  float*          bg2 = (float*)(WoT + 128 * 256);        // 256 f32

  prep_kernel<<<386, 256, 0, stream>>>(Wv, Wg, bg, Wo, W1T, WoT, bg2);

  float* Out = (float*)d_out;
  fused_kernel<<<256, 512, 0, stream>>>(X, W1T, WoT, bg2, bo, Out);
}